// Round 11
// baseline (340.311 us; speedup 1.0000x reference)
//
#include <hip/hip_runtime.h>
#include <hip/hip_bf16.h>

// Problem constants: N=64, C=64, T=128, V=25, H=3, DQ=32
// Inputs: float32. Output: float32 (compared under bf16-floored threshold).

#define WS_ATT    0         // 120000 floats: att_raw accumulator
#define WS_STATS  120000    // 128 floats: per-channel sum, sumsq (final)
#define WS_WBF    120128    // 30720 floats-worth = 61440 bf16: Wout as [tap][o][hc]
#define WS_WP     150848    // 6144 floats-worth = 12288 bf16: Wqkv as [n'][c]
#define WS_BP     156992    // 192 floats: bqkv reordered to n'
#define WS_PE     157184    // 1600 floats: pos-embed table [c][v]
#define WS_SPART  158784    // 8192 floats: per-tblock partial stats [64][128]
#define WS_ATTBF  166976    // 96000 floats-worth = 192000 bf16: att [n][h][v][u pad40]

typedef __attribute__((ext_vector_type(8))) short short8;   // 8 bf16 (4 VGPRs)
typedef __attribute__((ext_vector_type(4))) float floatx4;  // MFMA acc

__device__ __forceinline__ float us2f(unsigned short u) {
    union { unsigned int i; float f; } w; w.i = ((unsigned int)u) << 16; return w.f;
}
__device__ __forceinline__ unsigned short f2us(float f) {
    __hip_bfloat16_raw r = __float2bfloat16(f); return r.x;
}

// XOR-swizzle: 128B rows, 8 x 16B slots, slot ^= (col & 7). Returns byte offset.
__device__ __forceinline__ int swz(int col, int byteoff) {
    return col * 128 + ((((byteoff >> 4) ^ (col & 7)) << 4) | (byteoff & 15));
}

// lgkmcnt-only barrier: LDS ops drained, global loads stay in flight (T4).
__device__ __forceinline__ void bar_lgkm() {
    asm volatile("s_waitcnt lgkmcnt(0)" ::: "memory");
    __builtin_amdgcn_s_barrier();
}

// ---------------------------------------------------------------------------
// K0: prep constants.
// ---------------------------------------------------------------------------
__global__ void k_wprep(const float* __restrict__ Wout, const float* __restrict__ Wqkv,
                        const float* __restrict__ bqkv, unsigned short* __restrict__ Abf,
                        unsigned short* __restrict__ Wp, float* __restrict__ bp,
                        float* __restrict__ pe)
{
    int i = blockIdx.x * 256 + threadIdx.x;
    if (i < 61440) {
        int tap = i / 12288, rem = i % 12288;
        int o = rem / 192, hc = rem % 192;
        Abf[i] = f2us(Wout[o * 960 + hc * 5 + tap]);
    } else if (i < 73728) {
        int j = i - 61440;
        int np = j >> 6, c = j & 63;
        int h = np >> 6, qk = (np >> 5) & 1, cp = np & 31;
        Wp[j] = f2us(Wqkv[(qk * 96 + h * 32 + cp) * 64 + c]);
    } else if (i < 73920) {
        int np = i - 73728;
        int h = np >> 6, qk = (np >> 5) & 1, cp = np & 31;
        bp[np] = bqkv[qk * 96 + h * 32 + cp];
    } else if (i < 75520) {
        int e = i - 73920;
        int c = e / 25, v = e % 25;
        int ii = c >> 1;
        float d = expf(-(float)(2 * ii) * (9.210340371976184f / 64.0f));
        float a = (float)v * d;
        pe[e] = (c & 1) ? cosf(a) : sinf(a);
    }
}

// ---------------------------------------------------------------------------
// K1: att_raw accumulation, MFMA. Occupancy-dieted version:
//  - CPAD 104 (53.2 KB LDS total) -> 3 blocks/CU (was 78 KB -> 2)
//  - grid (16,64), 2 chunks/block -> 1024 blocks so the capacity is used
//  - pe in 32 registers/thread (loaded from peg), pe_s LDS eliminated
//  - single xs buffer (barrier before proj already fences prior readers)
//  - proj reads clamp col>99 -> 99; proj writes skip col>99 (outputs for
//    those lanes land in u,v>=25 rows which the flush discards anyway)
// ---------------------------------------------------------------------------
#define CPAD 104

__global__ __launch_bounds__(256, 3) void k_att(
    const float* __restrict__ x, const unsigned short* __restrict__ Wp,
    const float* __restrict__ bp, const float* __restrict__ peg,
    float* __restrict__ att_raw)
{
    __shared__ unsigned short xs_s[CPAD * 64];       // [col][c] bf16, swz (13312 B)
    __shared__ unsigned short qk_s[3 * CPAD * 64];   // [h][col][q|k] bf16 (39936 B)

    const int tid  = threadIdx.x;
    const int lane = tid & 63, wv = tid >> 6;
    const int l16  = lane & 15, quad = lane >> 4;
    const int n    = blockIdx.y;
    const int tb0  = blockIdx.x * 8;                 // 8 frames per block

    // staging per-thread constants: cols {lane, 64+lane(<100)}
    const int col_a = lane;
    const int col_b = 64 + lane;
    const int va = (col_a < 25) ? col_a : (col_a < 50 ? col_a - 25 : col_a - 50);
    const int vb = (col_b < 75) ? col_b - 50 : col_b - 75;
    char* xsb = (char*)xs_s;
    char* qkb = (char*)qk_s;

    // pe values this thread ever needs: 16 for col_a, 16 for col_b
    float pea[16], peb[16];
    #pragma unroll
    for (int k = 0; k < 16; ++k) {
        const int c = (wv * 8 + (k >> 1)) * 2 + (k & 1);
        pea[k] = peg[c * 25 + va];
    }
    if (lane < 36) {
        #pragma unroll
        for (int k = 0; k < 16; ++k) {
            const int c = (wv * 8 + (k >> 1)) * 2 + (k & 1);
            peb[k] = peg[c * 25 + vb];
        }
    }

    // Wp A-fragments + bias held in regs: wave wv owns out-ch tiles 3wv..3wv+2
    short8 afrag[3][2];
    float  biasr[3][4];
    #pragma unroll
    for (int mt = 0; mt < 3; ++mt) {
        int row = (3 * wv + mt) * 16 + l16;
        #pragma unroll
        for (int kk = 0; kk < 2; ++kk)
            afrag[mt][kk] = *(const short8*)(Wp + row * 64 + kk * 32 + quad * 8);
        #pragma unroll
        for (int reg = 0; reg < 4; ++reg)
            biasr[mt][reg] = bp[(3 * wv + mt) * 16 + quad * 4 + reg];
    }

    floatx4 qacc[3][2][2];
    #pragma unroll
    for (int h = 0; h < 3; ++h)
        #pragma unroll
        for (int a = 0; a < 2; ++a)
            #pragma unroll
            for (int b = 0; b < 2; ++b)
                qacc[h][a][b] = (floatx4){0.0f, 0.0f, 0.0f, 0.0f};

    #pragma unroll
    for (int ch = 0; ch < 2; ++ch) {
        const int g0 = (tb0 + ch * 4) * 25;   // global (t*25+v) base of chunk

        // ---- stage xs (x + pe -> bf16, pack c-pairs into u32) ----
        // safe vs prev chunk: bar before prev proj fenced all xs readers
        #pragma unroll
        for (int cp8 = 0; cp8 < 8; ++cp8) {
            const int cpair = wv * 8 + cp8;
            const int c0 = cpair * 2;
            const float* xp0 = x + (size_t)(n * 64 + c0) * 3200 + g0;
            const float* xp1 = xp0 + 3200;
            {
                unsigned int pk =
                    (unsigned int)f2us(xp0[col_a] + pea[2 * cp8]) |
                    ((unsigned int)f2us(xp1[col_a] + pea[2 * cp8 + 1]) << 16);
                *(unsigned int*)(xsb + swz(col_a, cpair * 4)) = pk;
            }
            if (lane < 36) {
                unsigned int pk =
                    (unsigned int)f2us(xp0[col_b] + peb[2 * cp8]) |
                    ((unsigned int)f2us(xp1[col_b] + peb[2 * cp8 + 1]) << 16);
                *(unsigned int*)(xsb + swz(col_b, cpair * 4)) = pk;
            }
        }
        bar_lgkm();   // xs ready

        // ---- projection: D[n'=out-ch][col], write b64 of 4 out-ch per lane ----
        #pragma unroll
        for (int nt = 0; nt < 7; ++nt) {
            const int col = nt * 16 + l16;
            const int colr = (col > 99) ? 99 : col;       // clamped read
            short8 b0 = *(const short8*)(xsb + swz(colr, quad * 16));
            short8 b1 = *(const short8*)(xsb + swz(colr, 64 + quad * 16));
            #pragma unroll
            for (int mt = 0; mt < 3; ++mt) {
                floatx4 acc = (floatx4){0.0f, 0.0f, 0.0f, 0.0f};
                acc = __builtin_amdgcn_mfma_f32_16x16x32_bf16(afrag[mt][0], b0, acc, 0, 0, 0);
                acc = __builtin_amdgcn_mfma_f32_16x16x32_bf16(afrag[mt][1], b1, acc, 0, 0, 0);
                if (col < 100) {
                    const int np  = (3 * wv + mt) * 16 + quad * 4;
                    const int h   = np >> 6;
                    const int off = (np & 63) * 2;            // q: 0..63, k: 64..127
                    unsigned long long pk =
                          (unsigned long long)f2us(acc[0] + biasr[mt][0])
                        | ((unsigned long long)f2us(acc[1] + biasr[mt][1]) << 16)
                        | ((unsigned long long)f2us(acc[2] + biasr[mt][2]) << 32)
                        | ((unsigned long long)f2us(acc[3] + biasr[mt][3]) << 48);
                    *(unsigned long long*)(qkb + h * (CPAD * 128) + swz(col, off)) = pk;
                }
            }
        }
        bar_lgkm();   // qk ready

        // ---- QK^T: wave wv handles frame t=wv of this chunk ----
        const int tcol = wv * 25;
        int chi = tcol + 16 + l16; if (chi > 99) chi = 99;   // clamped (u,v>=25 discarded)
        #pragma unroll
        for (int h = 0; h < 3; ++h) {
            char* qh = qkb + h * (CPAD * 128);
            short8 qa0 = *(const short8*)(qh + swz(tcol + l16, quad * 16));
            short8 qa1 = *(const short8*)(qh + swz(chi,        quad * 16));
            short8 kb0 = *(const short8*)(qh + swz(tcol + l16, 64 + quad * 16));
            short8 kb1 = *(const short8*)(qh + swz(chi,        64 + quad * 16));
            qacc[h][0][0] = __builtin_amdgcn_mfma_f32_16x16x32_bf16(qa0, kb0, qacc[h][0][0], 0, 0, 0);
            qacc[h][0][1] = __builtin_amdgcn_mfma_f32_16x16x32_bf16(qa0, kb1, qacc[h][0][1], 0, 0, 0);
            qacc[h][1][0] = __builtin_amdgcn_mfma_f32_16x16x32_bf16(qa1, kb0, qacc[h][1][0], 0, 0, 0);
            qacc[h][1][1] = __builtin_amdgcn_mfma_f32_16x16x32_bf16(qa1, kb1, qacc[h][1][1], 0, 0, 0);
        }
        bar_lgkm();   // qk reads done before next chunk overwrites (stage only touches xs,
                      // but proj of next chunk rewrites qk; this bar orders qkt vs next proj)
    }

    // ---- flush: wave accs -> LDS (aliased onto qk_s) -> global att_raw ----
    __syncthreads();
    float* att_s = (float*)qk_s;          // 7500 B alias (qk_s is 39936 B)
    for (int e = tid; e < 1875; e += 256) att_s[e] = 0.0f;
    __syncthreads();
    #pragma unroll
    for (int h = 0; h < 3; ++h) {
        #pragma unroll
        for (int ut = 0; ut < 2; ++ut) {
            #pragma unroll
            for (int vt = 0; vt < 2; ++vt) {
                const int v = vt * 16 + l16;
                if (v < 25) {
                    const int ub = ut * 16 + quad * 4;
                    #pragma unroll
                    for (int reg = 0; reg < 4; ++reg) {
                        const int u = ub + reg;
                        if (u < 25)
                            atomicAdd(&att_s[h * 625 + u * 25 + v], qacc[h][ut][vt][reg]);
                    }
                }
            }
        }
    }
    __syncthreads();
    for (int e = tid; e < 1875; e += 256)
        atomicAdd(&att_raw[(size_t)n * 1875 + e], att_s[e]);
}

// ---------------------------------------------------------------------------
// K1b: attbf[n][h][v][u pad40] = bf16( tanh(att_raw/4096)*alpha + att0 )
// Emits the conv kernel's LDS layout directly (transposed u<->v, zero pad).
// ---------------------------------------------------------------------------
__global__ void k_attfin(const float* __restrict__ att_raw,
                         unsigned short* __restrict__ attbf,
                         const float* __restrict__ alphas,
                         const float* __restrict__ att0s)
{
    int idx = blockIdx.x * 256 + threadIdx.x;
    if (idx >= 64 * 3 * 25 * 40) return;
    int u = idx % 40;
    int r = idx / 40;
    int v = r % 25;
    int nh = r / 25;
    int h = nh % 3;
    unsigned short val = 0;
    if (u < 25) {
        float a = att_raw[nh * 625 + u * 25 + v];
        val = f2us(tanhf(a * (1.0f / 4096.0f)) * alphas[h] + att0s[h * 625 + u * 25 + v]);
    }
    attbf[idx] = val;
}

// ---------------------------------------------------------------------------
// K2: MFMA implicit-GEMM conv — round-8 measured version (112 us), unchanged.
// ---------------------------------------------------------------------------
__global__ __launch_bounds__(256, 3) void k_conv(
    const float* __restrict__ x, const unsigned short* __restrict__ Abf,
    const float* __restrict__ bout, const unsigned short* __restrict__ attbf,
    float* __restrict__ out, float* __restrict__ spart)
{
    __shared__ unsigned short yT[11136];    // [t(2)][vv(29)][hc(192)] bf16, swizzled
    __shared__ unsigned short x_sb[4096];   // [c(64)][t(2)*32+u(pad32)] bf16, swz
    __shared__ unsigned short attT[3000];   // [h(3)][v(25)][u pad 40] bf16
    __shared__ float stats_s[128];

    const int tid = threadIdx.x;
    const int n = blockIdx.y;
    const int t0 = blockIdx.x * 2;
    char* xsb = (char*)x_sb;

    if (tid < 128) stats_s[tid] = 0.0f;

    // zero x_sb u-pad (u=25..31, both t): 64*2*7 = 896
    for (int e = tid; e < 896; e += 256) {
        int c = e / 14, r = e % 14;
        int t = r / 7, u = 25 + r % 7;
        *(unsigned short*)(xsb + swz(c, (t * 32 + u) * 2)) = 0;
    }
    // stage x -> bf16 (float2 loads)
    for (int e = tid; e < 1600; e += 256) {
        int c = e / 25, j = e % 25;
        const float2 xv = *(const float2*)(x + (size_t)(n * 64 + c) * 3200 + t0 * 25 + 2 * j);
        int i0 = 2 * j, i1 = i0 + 1;
        int p0 = (i0 / 25) * 32 + (i0 % 25);
        int p1 = (i1 / 25) * 32 + (i1 % 25);
        *(unsigned short*)(xsb + swz(c, p0 * 2)) = f2us(xv.x);
        *(unsigned short*)(xsb + swz(c, p1 * 2)) = f2us(xv.y);
    }
    // stage attT: linear copy (layout precomputed by k_attfin)
    {
        const uint4* src = (const uint4*)(attbf + (size_t)n * 3000);
        uint4* dst = (uint4*)attT;
        for (int e = tid; e < 375; e += 256) dst[e] = src[e];
    }
    // zero yT border cols vv in {0,1,27,28}
    for (int e = tid; e < 1536; e += 256) {
        int t = e / 768, r = e % 768;
        int vi = r / 192, hc = r % 192;
        int vv = (vi < 2) ? vi : (25 + vi);          // {0,1,27,28}
        int phys = (t * 29 + vv) * 192 + (((hc >> 3) ^ (vv & 7)) << 3) + (hc & 7);
        yT[phys] = 0;
    }
    __syncthreads();

    const int lane = tid & 63, wv = tid >> 6;
    const int quad = lane >> 4, l16 = lane & 15;

    // ---- phase A: y via MFMA. wave wv owns c-tile c0 = wv*16 ----
    {
        const int c0 = wv * 16;
        const int crow = c0 + l16;
        short8 af[2];
        #pragma unroll
        for (int t = 0; t < 2; ++t)
            af[t] = *(const short8*)(xsb + swz(crow, (t * 32 + quad * 8) * 2));
        short8 bfr[3][2];
        #pragma unroll
        for (int h = 0; h < 3; ++h)
            #pragma unroll
            for (int nt = 0; nt < 2; ++nt) {
                int v = nt * 16 + l16; if (v > 24) v = 24;   // clamp (garbage masked)
                bfr[h][nt] = *(const short8*)&attT[(h * 25 + v) * 40 + quad * 8];
            }
        #pragma unroll
        for (int t = 0; t < 2; ++t)
            #pragma unroll
            for (int h = 0; h < 3; ++h)
                #pragma unroll
                for (int nt = 0; nt < 2; ++nt) {
                    floatx4 d = (floatx4){0.0f, 0.0f, 0.0f, 0.0f};
                    d = __builtin_amdgcn_mfma_f32_16x16x32_bf16(af[t], bfr[h][nt], d, 0, 0, 0);
                    const int v = nt * 16 + l16;
                    if (v < 25) {
                        const int vv = v + 2;
                        const int hc = h * 64 + c0 + quad * 4;
                        const int phys = (t * 29 + vv) * 192 + (((hc >> 3) ^ (vv & 7)) << 3) + (hc & 7);
                        unsigned long long pk =
                              (unsigned long long)f2us(d[0])
                            | ((unsigned long long)f2us(d[1]) << 16)
                            | ((unsigned long long)f2us(d[2]) << 32)
                            | ((unsigned long long)f2us(d[3]) << 48);
                        *(unsigned long long*)&yT[phys] = pk;
                    }
                }
    }

    // ---- A-fragments for this wave's o-tile (plain loads, compiler-scheduled) ----
    const int o0 = wv * 16;
    short8 areg[5][6];
    const unsigned short* apb = Abf + (o0 + l16) * 192 + quad * 8;
    #pragma unroll
    for (int tap = 0; tap < 5; ++tap)
        #pragma unroll
        for (int kk = 0; kk < 6; ++kk)
            areg[tap][kk] = *(const short8*)(apb + tap * 12288 + kk * 32);
    float bo[4];
    #pragma unroll
    for (int reg = 0; reg < 4; ++reg) bo[reg] = bout[o0 + quad * 4 + reg];

    bar_lgkm();   // yT ds-writes drained; global loads in flight

    // ---- phase B: per wave 16(o) x 64(cols, masked to 50) x K=960 ----
    float s1[4] = {0, 0, 0, 0}, s2[4] = {0, 0, 0, 0};
    #pragma unroll
    for (int nt = 0; nt < 4; ++nt) {
        int col = nt * 16 + l16;
        const bool ok = col < 50;
        if (col > 49) col = 49;
        const int tc = col / 25, vc = col % 25;
        floatx4 acc = (floatx4){0.0f, 0.0f, 0.0f, 0.0f};
        #pragma unroll
        for (int tap = 0; tap < 5; ++tap) {
            const int vv = vc + tap;
            const int ro = (tc * 29 + vv) * 192, vx = vv & 7;
            #pragma unroll
            for (int kk = 0; kk < 6; ++kk) {
                short8 b = *(const short8*)&yT[ro + (((kk * 4 + quad) ^ vx) << 3)];
                acc = __builtin_amdgcn_mfma_f32_16x16x32_bf16(areg[tap][kk], b, acc, 0, 0, 0);
            }
        }
        float vr[4];
        #pragma unroll
        for (int reg = 0; reg < 4; ++reg)
            vr[reg] = ok ? acc[reg] + bo[reg] : 0.0f;
        if (ok) {
            float* op = out + (size_t)(n * 64 + o0 + quad * 4) * 3200 + (t0 + tc) * 25 + vc;
            #pragma unroll
            for (int reg = 0; reg < 4; ++reg)
                op[(size_t)reg * 3200] = vr[reg];
        }
        #pragma unroll
        for (int reg = 0; reg < 4; ++reg) {
            s1[reg] += vr[reg];
            s2[reg] = fmaf(vr[reg], vr[reg], s2[reg]);
        }
    }

    // ---- stats: 16-lane shfl reduce once, LDS accumulate, one global pass ----
    #pragma unroll
    for (int reg = 0; reg < 4; ++reg) {
        float a = s1[reg], b = s2[reg];
        #pragma unroll
        for (int m = 1; m < 16; m <<= 1) {
            a += __shfl_xor(a, m);
            b += __shfl_xor(b, m);
        }
        if (l16 == 0) {
            atomicAdd(&stats_s[o0 + quad * 4 + reg], a);
            atomicAdd(&stats_s[64 + o0 + quad * 4 + reg], b);
        }
    }
    __syncthreads();
    if (tid < 128)
        atomicAdd(&spart[(size_t)blockIdx.x * 128 + tid], stats_s[tid]);
}

// ---------------------------------------------------------------------------
// K3: reduce spart[64][128] -> stats[128]. One block.
// ---------------------------------------------------------------------------
__global__ void k_statsred(const float* __restrict__ spart, float* __restrict__ stats)
{
    int o = threadIdx.x;   // 0..127
    float s = 0.0f;
    #pragma unroll 8
    for (int t = 0; t < 64; ++t) s += spart[t * 128 + o];
    stats[o] = s;
}

// ---------------------------------------------------------------------------
// K4: out = leaky_relu( BN(conv) + x ), in place, float4-vectorized.
// ---------------------------------------------------------------------------
__global__ void k_final(const float* __restrict__ stats, const float4* __restrict__ x4,
                        const float* __restrict__ gamma, const float* __restrict__ beta,
                        float4* __restrict__ out4)
{
    int idx = blockIdx.x * 256 + threadIdx.x;
    if (idx >= 3276800) return;
    int o = (idx / 800) & 63;
    const float inv = 1.0f / 204800.0f;
    float m   = stats[o] * inv;
    float ex2 = stats[64 + o] * inv;
    float var = ex2 - m * m;
    float r = rsqrtf(var + 1e-5f);
    float g = gamma[o], bb = beta[o];
    float4 v = out4[idx];
    float4 xx = x4[idx];
    float4 res;
    float t;
    t = (v.x - m) * r * g + bb + xx.x; res.x = fmaxf(t, 0.1f * t);
    t = (v.y - m) * r * g + bb + xx.y; res.y = fmaxf(t, 0.1f * t);
    t = (v.z - m) * r * g + bb + xx.z; res.z = fmaxf(t, 0.1f * t);
    t = (v.w - m) * r * g + bb + xx.w; res.w = fmaxf(t, 0.1f * t);
    out4[idx] = res;
}

// ---------------------------------------------------------------------------
extern "C" void kernel_launch(void* const* d_in, const int* in_sizes, int n_in,
                              void* d_out, int out_size, void* d_ws, size_t ws_size,
                              hipStream_t stream)
{
    const float* x      = (const float*)d_in[0];
    const float* Wqkv   = (const float*)d_in[1];
    const float* bqkv   = (const float*)d_in[2];
    const float* alphas = (const float*)d_in[3];
    const float* att0s  = (const float*)d_in[4];
    const float* Wout   = (const float*)d_in[5];
    const float* bout   = (const float*)d_in[6];
    const float* gamma  = (const float*)d_in[7];
    const float* beta   = (const float*)d_in[8];
    float* ws  = (float*)d_ws;
    float* out = (float*)d_out;
    unsigned short* Abf   = (unsigned short*)(ws + WS_WBF);
    unsigned short* Wp    = (unsigned short*)(ws + WS_WP);
    float*          bp    = ws + WS_BP;
    float*          pe    = ws + WS_PE;
    float*          spart = ws + WS_SPART;
    unsigned short* attbf = (unsigned short*)(ws + WS_ATTBF);

    hipMemsetAsync(d_ws, 0, (size_t)120000 * sizeof(float), stream);
    hipMemsetAsync(spart, 0, (size_t)8192 * sizeof(float), stream);

    k_wprep   <<<296, 256, 0, stream>>>(Wout, Wqkv, bqkv, Abf, Wp, bp, pe);
    k_att     <<<dim3(16, 64), 256, 0, stream>>>(x, Wp, bp, pe, ws + WS_ATT);
    k_attfin  <<<750, 256, 0, stream>>>(ws + WS_ATT, attbf, alphas, att0s);
    k_conv    <<<dim3(64, 64), 256, 0, stream>>>(x, Abf, bout, attbf, out, spart);
    k_statsred<<<1, 128, 0, stream>>>(spart, ws + WS_STATS);
    k_final   <<<12800, 256, 0, stream>>>(ws + WS_STATS, (const float4*)x,
                                          gamma, beta, (float4*)out);
}

// Round 13
// 250.146 us; speedup vs baseline: 1.3604x; 1.3604x over previous
//
#include <hip/hip_runtime.h>
#include <hip/hip_bf16.h>

// Problem constants: N=64, C=64, T=128, V=25, H=3, DQ=32
// Inputs: float32. Output: float32 (compared under bf16-floored threshold).

#define WS_ATT    0         // 120000 floats: att_raw accumulator
#define WS_STATS  120000    // 128 floats: per-channel sum, sumsq (final)
#define WS_WBF    120128    // 30720 floats-worth = 61440 bf16: Wout as [tap][o][hc]
#define WS_WP     150848    // 6144 floats-worth = 12288 bf16: Wqkv as [n'][c]
#define WS_BP     156992    // 192 floats: bqkv reordered to n'
#define WS_PE     157184    // 1600 floats: pos-embed table [c][v]
#define WS_SPART  158784    // 8192 floats: per-tblock partial stats [64][128]
#define WS_ATTBF  166976    // 96000 floats-worth = 192000 bf16: att [n][h][v][u pad40]

typedef __attribute__((ext_vector_type(8))) short short8;   // 8 bf16 (4 VGPRs)
typedef __attribute__((ext_vector_type(4))) float floatx4;  // MFMA acc

__device__ __forceinline__ float us2f(unsigned short u) {
    union { unsigned int i; float f; } w; w.i = ((unsigned int)u) << 16; return w.f;
}
__device__ __forceinline__ unsigned short f2us(float f) {
    __hip_bfloat16_raw r = __float2bfloat16(f); return r.x;
}

// XOR-swizzle: 128B rows, 8 x 16B slots, slot ^= (col & 7). Returns byte offset.
__device__ __forceinline__ int swz(int col, int byteoff) {
    return col * 128 + ((((byteoff >> 4) ^ (col & 7)) << 4) | (byteoff & 15));
}

// lgkmcnt-only barrier: LDS ops drained, global loads stay in flight (T4).
__device__ __forceinline__ void bar_lgkm() {
    asm volatile("s_waitcnt lgkmcnt(0)" ::: "memory");
    __builtin_amdgcn_s_barrier();
}

// ---------------------------------------------------------------------------
// K0: prep constants.
// ---------------------------------------------------------------------------
__global__ void k_wprep(const float* __restrict__ Wout, const float* __restrict__ Wqkv,
                        const float* __restrict__ bqkv, unsigned short* __restrict__ Abf,
                        unsigned short* __restrict__ Wp, float* __restrict__ bp,
                        float* __restrict__ pe)
{
    int i = blockIdx.x * 256 + threadIdx.x;
    if (i < 61440) {
        int tap = i / 12288, rem = i % 12288;
        int o = rem / 192, hc = rem % 192;
        Abf[i] = f2us(Wout[o * 960 + hc * 5 + tap]);
    } else if (i < 73728) {
        int j = i - 61440;
        int np = j >> 6, c = j & 63;
        int h = np >> 6, qk = (np >> 5) & 1, cp = np & 31;
        Wp[j] = f2us(Wqkv[(qk * 96 + h * 32 + cp) * 64 + c]);
    } else if (i < 73920) {
        int np = i - 73728;
        int h = np >> 6, qk = (np >> 5) & 1, cp = np & 31;
        bp[np] = bqkv[qk * 96 + h * 32 + cp];
    } else if (i < 75520) {
        int e = i - 73920;
        int c = e / 25, v = e % 25;
        int ii = c >> 1;
        float d = expf(-(float)(2 * ii) * (9.210340371976184f / 64.0f));
        float a = (float)v * d;
        pe[e] = (c & 1) ? cosf(a) : sinf(a);
    }
}

// ---------------------------------------------------------------------------
// K1: att_raw accumulation — R8-measured pipelined version (~41 us), restored
// verbatim. LOADCH register prefetch (T14) hides HBM x-load latency under
// proj+qkt; CPAD 112, double-buffered xs, lgkm-only barriers.
// ---------------------------------------------------------------------------
#define CPAD 112

__global__ __launch_bounds__(256, 2) void k_att(
    const float* __restrict__ x, const unsigned short* __restrict__ Wp,
    const float* __restrict__ bp, const float* __restrict__ peg,
    float* __restrict__ att_raw)
{
    __shared__ unsigned short xs_s[2][CPAD * 64];    // [buf][col][c] bf16, swz
    __shared__ unsigned short qk_s[3 * CPAD * 64];   // [h][col][q|k] bf16, swz
    __shared__ float pe_s[1600];                     // [c][v] fp32

    const int tid  = threadIdx.x;
    const int lane = tid & 63, wv = tid >> 6;
    const int l16  = lane & 15, quad = lane >> 4;
    const int n    = blockIdx.y;
    const int tb0  = blockIdx.x * 16;

    const int col_a = lane;
    const int col_b = 64 + lane;
    const int va = (col_a < 25) ? col_a : (col_a < 50 ? col_a - 25 : col_a - 50);
    const int vb = (col_b < 75) ? col_b - 50 : col_b - 75;
    char* qkb = (char*)qk_s;

    float ra0[8], ra1[8], rb0[8], rb1[8];   // staged x values (T14 issue-early)

#define LOADCH(CH) do {                                                         \
    const int g0_ = (tb0 + (CH) * 4) * 25;                                      \
    _Pragma("unroll")                                                           \
    for (int cp8 = 0; cp8 < 8; ++cp8) {                                         \
        const float* xp0_ = x + (size_t)(n * 64 + (wv * 8 + cp8) * 2) * 3200 + g0_; \
        const float* xp1_ = xp0_ + 3200;                                        \
        ra0[cp8] = xp0_[col_a]; ra1[cp8] = xp1_[col_a];                         \
        if (lane < 36) { rb0[cp8] = xp0_[col_b]; rb1[cp8] = xp1_[col_b]; }      \
    } } while (0)

    LOADCH(0);

    for (int e = tid; e < 1600; e += 256) pe_s[e] = peg[e];

    short8 afrag[3][2];
    float  biasr[3][4];
    #pragma unroll
    for (int mt = 0; mt < 3; ++mt) {
        int row = (3 * wv + mt) * 16 + l16;
        #pragma unroll
        for (int kk = 0; kk < 2; ++kk)
            afrag[mt][kk] = *(const short8*)(Wp + row * 64 + kk * 32 + quad * 8);
        #pragma unroll
        for (int reg = 0; reg < 4; ++reg)
            biasr[mt][reg] = bp[(3 * wv + mt) * 16 + quad * 4 + reg];
    }

    floatx4 qacc[3][2][2];
    #pragma unroll
    for (int h = 0; h < 3; ++h)
        #pragma unroll
        for (int a = 0; a < 2; ++a)
            #pragma unroll
            for (int b = 0; b < 2; ++b)
                qacc[h][a][b] = (floatx4){0.0f, 0.0f, 0.0f, 0.0f};

    bar_lgkm();   // pe_s ready; LOADCH(0) globals in flight

    #pragma unroll
    for (int ch = 0; ch < 4; ++ch) {
        char* xsb = (char*)xs_s[ch & 1];

        #pragma unroll
        for (int cp8 = 0; cp8 < 8; ++cp8) {
            const int cpair = wv * 8 + cp8, c0 = cpair * 2;
            unsigned int pk =
                (unsigned int)f2us(ra0[cp8] + pe_s[c0 * 25 + va]) |
                ((unsigned int)f2us(ra1[cp8] + pe_s[c0 * 25 + 25 + va]) << 16);
            *(unsigned int*)(xsb + swz(col_a, cpair * 4)) = pk;
            if (lane < 36) {
                pk = (unsigned int)f2us(rb0[cp8] + pe_s[c0 * 25 + vb]) |
                     ((unsigned int)f2us(rb1[cp8] + pe_s[c0 * 25 + 25 + vb]) << 16);
                *(unsigned int*)(xsb + swz(col_b, cpair * 4)) = pk;
            }
        }
        if (ch < 3) LOADCH(ch + 1);
        bar_lgkm();   // xs ready

        #pragma unroll
        for (int nt = 0; nt < 7; ++nt) {
            const int col = nt * 16 + l16;
            short8 b0 = *(const short8*)(xsb + swz(col, quad * 16));
            short8 b1 = *(const short8*)(xsb + swz(col, 64 + quad * 16));
            #pragma unroll
            for (int mt = 0; mt < 3; ++mt) {
                floatx4 acc = (floatx4){0.0f, 0.0f, 0.0f, 0.0f};
                acc = __builtin_amdgcn_mfma_f32_16x16x32_bf16(afrag[mt][0], b0, acc, 0, 0, 0);
                acc = __builtin_amdgcn_mfma_f32_16x16x32_bf16(afrag[mt][1], b1, acc, 0, 0, 0);
                const int np  = (3 * wv + mt) * 16 + quad * 4;
                const int h   = np >> 6;
                const int off = (np & 63) * 2;
                unsigned long long pk =
                      (unsigned long long)f2us(acc[0] + biasr[mt][0])
                    | ((unsigned long long)f2us(acc[1] + biasr[mt][1]) << 16)
                    | ((unsigned long long)f2us(acc[2] + biasr[mt][2]) << 32)
                    | ((unsigned long long)f2us(acc[3] + biasr[mt][3]) << 48);
                *(unsigned long long*)(qkb + h * (CPAD * 128) + swz(col, off)) = pk;
            }
        }
        bar_lgkm();   // qk ready

        const int tcol = wv * 25;
        #pragma unroll
        for (int h = 0; h < 3; ++h) {
            char* qh = qkb + h * (CPAD * 128);
            short8 qa0 = *(const short8*)(qh + swz(tcol + l16,      quad * 16));
            short8 qa1 = *(const short8*)(qh + swz(tcol + 16 + l16, quad * 16));
            short8 kb0 = *(const short8*)(qh + swz(tcol + l16,      64 + quad * 16));
            short8 kb1 = *(const short8*)(qh + swz(tcol + 16 + l16, 64 + quad * 16));
            qacc[h][0][0] = __builtin_amdgcn_mfma_f32_16x16x32_bf16(qa0, kb0, qacc[h][0][0], 0, 0, 0);
            qacc[h][0][1] = __builtin_amdgcn_mfma_f32_16x16x32_bf16(qa0, kb1, qacc[h][0][1], 0, 0, 0);
            qacc[h][1][0] = __builtin_amdgcn_mfma_f32_16x16x32_bf16(qa1, kb0, qacc[h][1][0], 0, 0, 0);
            qacc[h][1][1] = __builtin_amdgcn_mfma_f32_16x16x32_bf16(qa1, kb1, qacc[h][1][1], 0, 0, 0);
        }
    }

    // ---- flush: wave accs -> LDS (aliased onto qk_s) -> global att_raw ----
    __syncthreads();
    float* att_s = (float*)qk_s;
    for (int e = tid; e < 1875; e += 256) att_s[e] = 0.0f;
    __syncthreads();
    #pragma unroll
    for (int h = 0; h < 3; ++h) {
        #pragma unroll
        for (int ut = 0; ut < 2; ++ut) {
            #pragma unroll
            for (int vt = 0; vt < 2; ++vt) {
                const int v = vt * 16 + l16;
                if (v < 25) {
                    const int ub = ut * 16 + quad * 4;
                    #pragma unroll
                    for (int reg = 0; reg < 4; ++reg) {
                        const int u = ub + reg;
                        if (u < 25)
                            atomicAdd(&att_s[h * 625 + u * 25 + v], qacc[h][ut][vt][reg]);
                    }
                }
            }
        }
    }
    __syncthreads();
    for (int e = tid; e < 1875; e += 256)
        atomicAdd(&att_raw[(size_t)n * 1875 + e], att_s[e]);
}

// ---------------------------------------------------------------------------
// K1b: attbf[n][h][v][u pad40] = bf16( tanh(att_raw/4096)*alpha + att0 )
// Emits the conv kernel's LDS layout directly (transposed u<->v, zero pad).
// ---------------------------------------------------------------------------
__global__ void k_attfin(const float* __restrict__ att_raw,
                         unsigned short* __restrict__ attbf,
                         const float* __restrict__ alphas,
                         const float* __restrict__ att0s)
{
    int idx = blockIdx.x * 256 + threadIdx.x;
    if (idx >= 64 * 3 * 25 * 40) return;
    int u = idx % 40;
    int r = idx / 40;
    int v = r % 25;
    int nh = r / 25;
    int h = nh % 3;
    unsigned short val = 0;
    if (u < 25) {
        float a = att_raw[nh * 625 + u * 25 + v];
        val = f2us(tanhf(a * (1.0f / 4096.0f)) * alphas[h] + att0s[h * 625 + u * 25 + v]);
    }
    attbf[idx] = val;
}

// ---------------------------------------------------------------------------
// K2: MFMA implicit-GEMM conv. Phase B loop-swapped: each A-frag loaded ONCE
// (global, L2-resident) and shared by 4 col-tile MFMAs into 4 INDEPENDENT
// accumulators — cuts A L2-loads 4x and breaks the serial 30-MFMA chain.
// ---------------------------------------------------------------------------
__global__ __launch_bounds__(256, 3) void k_conv(
    const float* __restrict__ x, const unsigned short* __restrict__ Abf,
    const float* __restrict__ bout, const unsigned short* __restrict__ attbf,
    float* __restrict__ out, float* __restrict__ spart)
{
    __shared__ unsigned short yT[11136];    // [t(2)][vv(29)][hc(192)] bf16, swizzled
    __shared__ unsigned short x_sb[4096];   // [c(64)][t(2)*32+u(pad32)] bf16, swz
    __shared__ unsigned short attT[3000];   // [h(3)][v(25)][u pad 40] bf16
    __shared__ float stats_s[128];

    const int tid = threadIdx.x;
    const int n = blockIdx.y;
    const int t0 = blockIdx.x * 2;
    char* xsb = (char*)x_sb;

    if (tid < 128) stats_s[tid] = 0.0f;

    // zero x_sb u-pad (u=25..31, both t): 64*2*7 = 896
    for (int e = tid; e < 896; e += 256) {
        int c = e / 14, r = e % 14;
        int t = r / 7, u = 25 + r % 7;
        *(unsigned short*)(xsb + swz(c, (t * 32 + u) * 2)) = 0;
    }
    // stage x -> bf16 (float2 loads)
    for (int e = tid; e < 1600; e += 256) {
        int c = e / 25, j = e % 25;
        const float2 xv = *(const float2*)(x + (size_t)(n * 64 + c) * 3200 + t0 * 25 + 2 * j);
        int i0 = 2 * j, i1 = i0 + 1;
        int p0 = (i0 / 25) * 32 + (i0 % 25);
        int p1 = (i1 / 25) * 32 + (i1 % 25);
        *(unsigned short*)(xsb + swz(c, p0 * 2)) = f2us(xv.x);
        *(unsigned short*)(xsb + swz(c, p1 * 2)) = f2us(xv.y);
    }
    // stage attT: linear copy (layout precomputed by k_attfin)
    {
        const uint4* src = (const uint4*)(attbf + (size_t)n * 3000);
        uint4* dst = (uint4*)attT;
        for (int e = tid; e < 375; e += 256) dst[e] = src[e];
    }
    // zero yT border cols vv in {0,1,27,28}
    for (int e = tid; e < 1536; e += 256) {
        int t = e / 768, r = e % 768;
        int vi = r / 192, hc = r % 192;
        int vv = (vi < 2) ? vi : (25 + vi);          // {0,1,27,28}
        int phys = (t * 29 + vv) * 192 + (((hc >> 3) ^ (vv & 7)) << 3) + (hc & 7);
        yT[phys] = 0;
    }
    __syncthreads();

    const int lane = tid & 63, wv = tid >> 6;
    const int quad = lane >> 4, l16 = lane & 15;

    // ---- phase A: y via MFMA. wave wv owns c-tile c0 = wv*16 ----
    {
        const int c0 = wv * 16;
        const int crow = c0 + l16;
        short8 af[2];
        #pragma unroll
        for (int t = 0; t < 2; ++t)
            af[t] = *(const short8*)(xsb + swz(crow, (t * 32 + quad * 8) * 2));
        short8 bfr[3][2];
        #pragma unroll
        for (int h = 0; h < 3; ++h)
            #pragma unroll
            for (int nt = 0; nt < 2; ++nt) {
                int v = nt * 16 + l16; if (v > 24) v = 24;   // clamp (garbage masked)
                bfr[h][nt] = *(const short8*)&attT[(h * 25 + v) * 40 + quad * 8];
            }
        #pragma unroll
        for (int t = 0; t < 2; ++t)
            #pragma unroll
            for (int h = 0; h < 3; ++h)
                #pragma unroll
                for (int nt = 0; nt < 2; ++nt) {
                    floatx4 d = (floatx4){0.0f, 0.0f, 0.0f, 0.0f};
                    d = __builtin_amdgcn_mfma_f32_16x16x32_bf16(af[t], bfr[h][nt], d, 0, 0, 0);
                    const int v = nt * 16 + l16;
                    if (v < 25) {
                        const int vv = v + 2;
                        const int hc = h * 64 + c0 + quad * 4;
                        const int phys = (t * 29 + vv) * 192 + (((hc >> 3) ^ (vv & 7)) << 3) + (hc & 7);
                        unsigned long long pk =
                              (unsigned long long)f2us(d[0])
                            | ((unsigned long long)f2us(d[1]) << 16)
                            | ((unsigned long long)f2us(d[2]) << 32)
                            | ((unsigned long long)f2us(d[3]) << 48);
                        *(unsigned long long*)&yT[phys] = pk;
                    }
                }
    }

    const int o0 = wv * 16;
    const unsigned short* apb = Abf + (o0 + l16) * 192 + quad * 8;
    float bo[4];
    #pragma unroll
    for (int reg = 0; reg < 4; ++reg) bo[reg] = bout[o0 + quad * 4 + reg];

    bar_lgkm();   // yT ds-writes drained; bo loads in flight

    // ---- phase B: per wave 16(o) x 64(cols, masked to 50) x K=960 ----
    // Loop-swapped: A once per (tap,kk), 4 independent acc chains.
    int tcv[4], vcv[4];
    bool okv[4];
    #pragma unroll
    for (int nt = 0; nt < 4; ++nt) {
        int col = nt * 16 + l16;
        okv[nt] = col < 50;
        if (col > 49) col = 49;
        tcv[nt] = col / 25; vcv[nt] = col % 25;
    }
    floatx4 acc0 = {0,0,0,0}, acc1 = {0,0,0,0}, acc2 = {0,0,0,0}, acc3 = {0,0,0,0};
    #pragma unroll
    for (int tap = 0; tap < 5; ++tap) {
        #pragma unroll
        for (int kk = 0; kk < 6; ++kk) {
            short8 a = *(const short8*)(apb + tap * 12288 + kk * 32);
            const int hb = (kk * 4 + quad);
            {
                const int vv = vcv[0] + tap;
                short8 b = *(const short8*)&yT[(tcv[0] * 29 + vv) * 192 + ((hb ^ (vv & 7)) << 3)];
                acc0 = __builtin_amdgcn_mfma_f32_16x16x32_bf16(a, b, acc0, 0, 0, 0);
            }
            {
                const int vv = vcv[1] + tap;
                short8 b = *(const short8*)&yT[(tcv[1] * 29 + vv) * 192 + ((hb ^ (vv & 7)) << 3)];
                acc1 = __builtin_amdgcn_mfma_f32_16x16x32_bf16(a, b, acc1, 0, 0, 0);
            }
            {
                const int vv = vcv[2] + tap;
                short8 b = *(const short8*)&yT[(tcv[2] * 29 + vv) * 192 + ((hb ^ (vv & 7)) << 3)];
                acc2 = __builtin_amdgcn_mfma_f32_16x16x32_bf16(a, b, acc2, 0, 0, 0);
            }
            {
                const int vv = vcv[3] + tap;
                short8 b = *(const short8*)&yT[(tcv[3] * 29 + vv) * 192 + ((hb ^ (vv & 7)) << 3)];
                acc3 = __builtin_amdgcn_mfma_f32_16x16x32_bf16(a, b, acc3, 0, 0, 0);
            }
        }
    }

    // ---- epilogue: store + per-channel stats (channel = o0+quad*4+reg) ----
    float s1[4] = {0, 0, 0, 0}, s2[4] = {0, 0, 0, 0};
#define EPIS(ACC, NT)                                                          \
    do {                                                                       \
        float vr[4];                                                           \
        _Pragma("unroll")                                                      \
        for (int reg = 0; reg < 4; ++reg)                                      \
            vr[reg] = okv[NT] ? ACC[reg] + bo[reg] : 0.0f;                     \
        if (okv[NT]) {                                                         \
            float* op = out + (size_t)(n * 64 + o0 + quad * 4) * 3200          \
                        + (t0 + tcv[NT]) * 25 + vcv[NT];                       \
            _Pragma("unroll")                                                  \
            for (int reg = 0; reg < 4; ++reg)                                  \
                op[(size_t)reg * 3200] = vr[reg];                              \
        }                                                                      \
        _Pragma("unroll")                                                      \
        for (int reg = 0; reg < 4; ++reg) {                                    \
            s1[reg] += vr[reg];                                                \
            s2[reg] = fmaf(vr[reg], vr[reg], s2[reg]);                         \
        }                                                                      \
    } while (0)

    EPIS(acc0, 0); EPIS(acc1, 1); EPIS(acc2, 2); EPIS(acc3, 3);
#undef EPIS

    // ---- stats: 16-lane shfl reduce once, LDS accumulate, one global pass ----
    #pragma unroll
    for (int reg = 0; reg < 4; ++reg) {
        float a = s1[reg], b = s2[reg];
        #pragma unroll
        for (int m = 1; m < 16; m <<= 1) {
            a += __shfl_xor(a, m);
            b += __shfl_xor(b, m);
        }
        if (l16 == 0) {
            atomicAdd(&stats_s[o0 + quad * 4 + reg], a);
            atomicAdd(&stats_s[64 + o0 + quad * 4 + reg], b);
        }
    }
    __syncthreads();
    if (tid < 128)
        atomicAdd(&spart[(size_t)blockIdx.x * 128 + tid], stats_s[tid]);
}

// ---------------------------------------------------------------------------
// K3: reduce spart[64][128] -> stats[128]. One block.
// ---------------------------------------------------------------------------
__global__ void k_statsred(const float* __restrict__ spart, float* __restrict__ stats)
{
    int o = threadIdx.x;   // 0..127
    float s = 0.0f;
    #pragma unroll 8
    for (int t = 0; t < 64; ++t) s += spart[t * 128 + o];
    stats[o] = s;
}

// ---------------------------------------------------------------------------
// K4: out = leaky_relu( BN(conv) + x ), in place, float4-vectorized.
// ---------------------------------------------------------------------------
__global__ void k_final(const float* __restrict__ stats, const float4* __restrict__ x4,
                        const float* __restrict__ gamma, const float* __restrict__ beta,
                        float4* __restrict__ out4)
{
    int idx = blockIdx.x * 256 + threadIdx.x;
    if (idx >= 3276800) return;
    int o = (idx / 800) & 63;
    const float inv = 1.0f / 204800.0f;
    float m   = stats[o] * inv;
    float ex2 = stats[64 + o] * inv;
    float var = ex2 - m * m;
    float r = rsqrtf(var + 1e-5f);
    float g = gamma[o], bb = beta[o];
    float4 v = out4[idx];
    float4 xx = x4[idx];
    float4 res;
    float t;
    t = (v.x - m) * r * g + bb + xx.x; res.x = fmaxf(t, 0.1f * t);
    t = (v.y - m) * r * g + bb + xx.y; res.y = fmaxf(t, 0.1f * t);
    t = (v.z - m) * r * g + bb + xx.z; res.z = fmaxf(t, 0.1f * t);
    t = (v.w - m) * r * g + bb + xx.w; res.w = fmaxf(t, 0.1f * t);
    out4[idx] = res;
}

// ---------------------------------------------------------------------------
extern "C" void kernel_launch(void* const* d_in, const int* in_sizes, int n_in,
                              void* d_out, int out_size, void* d_ws, size_t ws_size,
                              hipStream_t stream)
{
    const float* x      = (const float*)d_in[0];
    const float* Wqkv   = (const float*)d_in[1];
    const float* bqkv   = (const float*)d_in[2];
    const float* alphas = (const float*)d_in[3];
    const float* att0s  = (const float*)d_in[4];
    const float* Wout   = (const float*)d_in[5];
    const float* bout   = (const float*)d_in[6];
    const float* gamma  = (const float*)d_in[7];
    const float* beta   = (const float*)d_in[8];
    float* ws  = (float*)d_ws;
    float* out = (float*)d_out;
    unsigned short* Abf   = (unsigned short*)(ws + WS_WBF);
    unsigned short* Wp    = (unsigned short*)(ws + WS_WP);
    float*          bp    = ws + WS_BP;
    float*          pe    = ws + WS_PE;
    float*          spart = ws + WS_SPART;
    unsigned short* attbf = (unsigned short*)(ws + WS_ATTBF);

    hipMemsetAsync(d_ws, 0, (size_t)120000 * sizeof(float), stream);
    hipMemsetAsync(spart, 0, (size_t)8192 * sizeof(float), stream);

    k_wprep   <<<296, 256, 0, stream>>>(Wout, Wqkv, bqkv, Abf, Wp, bp, pe);
    k_att     <<<dim3(8, 64),  256, 0, stream>>>(x, Wp, bp, pe, ws + WS_ATT);
    k_attfin  <<<750, 256, 0, stream>>>(ws + WS_ATT, attbf, alphas, att0s);
    k_conv    <<<dim3(64, 64), 256, 0, stream>>>(x, Abf, bout, attbf, out, spart);
    k_statsred<<<1, 128, 0, stream>>>(spart, ws + WS_STATS);
    k_final   <<<12800, 256, 0, stream>>>(ws + WS_STATS, (const float4*)x,
                                          gamma, beta, (float4*)out);
}